// Round 7
// baseline (90.087 us; speedup 1.0000x reference)
//
#include <hip/hip_runtime.h>

// NcutLoss: N=4, K=8, C=3, H=W=1024, S=1000, R=5, P=81 disk points.
// loss = N*K - sum_{n,k} num[n,k]/den[n,k]
//   num[n,k] = sum_{s,p} wgt*q*pc ; den[n,k] = sum_s pc*sum_p wgt
//   wgt = exp(-d2/SIGMA_I^2 - (di^2+dj^2)/SIGMA_X^2)
//
// R6: fuse accum + final into ONE kernel (last-block-done pattern) to remove
// one graph node + one dispatch. Gather core identical to R5 (best measured):
// two waves per (n,s) split by disk row, no redundant lines, 8000 waves.
// Init (stripes + counter) via one tiny memset node. Last block re-reads
// stripes with device-scope atomic loads (cross-XCD safe) and writes out.

constexpr int P = 81;
constexpr int WW = 1024;
constexpr size_t HW = (size_t)1024 * 1024;
constexpr int NN = 4, KK = 8, CC = 3;
constexpr int NSTRIPE = 64;
constexpr float INV_SI2 = 1.0f / 100.0f;  // 1/SIGMA_I^2
constexpr float INV_SX2 = 1.0f / 16.0f;   // 1/SIGMA_X^2

// Disk offsets, row-major over di=-5..5. p 0..34: rows -5..-1 (35 pts),
// p 35..80: rows 0..+5 (46 pts).
__device__ __constant__ signed char c_di[P] = {
    -5,
    -4,-4,-4,-4,-4,-4,-4,
    -3,-3,-3,-3,-3,-3,-3,-3,-3,
    -2,-2,-2,-2,-2,-2,-2,-2,-2,
    -1,-1,-1,-1,-1,-1,-1,-1,-1,
     0, 0, 0, 0, 0, 0, 0, 0, 0, 0, 0,
     1, 1, 1, 1, 1, 1, 1, 1, 1,
     2, 2, 2, 2, 2, 2, 2, 2, 2,
     3, 3, 3, 3, 3, 3, 3, 3, 3,
     4, 4, 4, 4, 4, 4, 4,
     5
};
__device__ __constant__ signed char c_dj[P] = {
     0,
    -3,-2,-1, 0, 1, 2, 3,
    -4,-3,-2,-1, 0, 1, 2, 3, 4,
    -4,-3,-2,-1, 0, 1, 2, 3, 4,
    -4,-3,-2,-1, 0, 1, 2, 3, 4,
    -5,-4,-3,-2,-1, 0, 1, 2, 3, 4, 5,
    -4,-3,-2,-1, 0, 1, 2, 3, 4,
    -4,-3,-2,-1, 0, 1, 2, 3, 4,
    -4,-3,-2,-1, 0, 1, 2, 3, 4,
    -3,-2,-1, 0, 1, 2, 3,
     0
};

__global__ __launch_bounds__(256) void ncut_fused(
    const float* __restrict__ pred,   // (N,K,H,W)
    const float* __restrict__ imgs,   // (N,C,H,W)
    const long long* __restrict__ hs, // (S,)
    const long long* __restrict__ wsm,// (S,)
    float* __restrict__ acc,          // NSTRIPE x 64 floats (zeroed by memset)
    int* __restrict__ counter,        // zeroed by memset
    float* __restrict__ out,
    int S, int totalBlocks)
{
    const int tid  = threadIdx.x;
    const int lane = tid & 63;
    const int wv   = tid >> 6;        // 0..3
    const int sl   = wv >> 1;         // local sample 0..1
    const int half = wv & 1;          // 0: disk rows -5..-1, 1: rows 0..+5

    const int n = blockIdx.y;
    const int s = blockIdx.x * 2 + sl;

    if (s < S) {
        const int h = (int)hs[s] + 5;
        const int w = (int)wsm[s] + 5;
        const float* img_n = imgs + (size_t)n * CC * HW;
        const size_t coff = (size_t)h * WW + w;
        const float* pn = pred + (size_t)n * KK * HW;

        // Prefetch center preds on lanes 0..7 (latency hidden under gather).
        float pv = 0.0f;
        if (lane < KK) pv = pn[(size_t)lane * HW + coff];

        const float c0 = img_n[coff];
        const float c1 = img_n[HW + coff];
        const float c2 = img_n[2 * HW + coff];

        const int base = half ? 35 : 0;
        const int npts = half ? 46 : 35;

        float wsum = 0.0f;
        float qw[KK] = {0.f,0.f,0.f,0.f,0.f,0.f,0.f,0.f};

        if (lane < npts) {
            const int p  = base + lane;
            const int di = (int)c_di[p];
            const int dj = (int)c_dj[p];
            const size_t off = (size_t)(h + di) * WW + (w + dj);
            const float d0 = img_n[off]          - c0;
            const float d1 = img_n[HW + off]     - c1;
            const float d2 = img_n[2 * HW + off] - c2;
            const float r2 = (float)(di * di + dj * dj);
            const float wgt = __expf(-((d0*d0 + d1*d1 + d2*d2) * INV_SI2
                                       + r2 * INV_SX2));
            wsum = wgt;
            const float* qb = pn + off;
            #pragma unroll
            for (int k = 0; k < KK; ++k)
                qw[k] = wgt * qb[(size_t)k * HW];
        }

        #pragma unroll
        for (int off = 32; off; off >>= 1) {
            wsum += __shfl_xor(wsum, off);
            #pragma unroll
            for (int k = 0; k < KK; ++k)
                qw[k] += __shfl_xor(qw[k], off);
        }

        // 16-lane parallel epilogue: lanes 0..7 num[k], lanes 8..15 den[k].
        if (lane < 16) {
            const int k = lane & 7;
            const float pvv = __shfl(pv, k);
            float q = qw[0];
            #pragma unroll
            for (int j = 1; j < KK; ++j)
                if (k == j) q = qw[j];
            const float val = (lane < 8) ? pvv * q : pvv * wsum;
            float* st = acc + (size_t)(blockIdx.x & (NSTRIPE - 1)) * 64;
            atomicAdd(&st[(lane < 8 ? 0 : 32) + n * KK + k], val);
        }
    }

    // ---- completion protocol ----
    __shared__ int lastFlag;
    __syncthreads();
    if (tid == 0) {
        __threadfence();                       // make stripe atomics visible
        const int old = atomicAdd(counter, 1); // device scope
        lastFlag = (old == totalBlocks - 1) ? 1 : 0;
    }
    __syncthreads();
    if (!lastFlag) return;
    __threadfence();

    // ---- final reduction by the last block (256 threads) ----
    __shared__ float L[4][64];
    const int j    = tid & 63;
    const int part = tid >> 6;
    float v = 0.0f;
    #pragma unroll 4
    for (int st = part; st < NSTRIPE; st += 4)
        v += __hip_atomic_load(&acc[st * 64 + j], __ATOMIC_RELAXED,
                               __HIP_MEMORY_SCOPE_AGENT);
    L[part][j] = v;
    __syncthreads();
    if (tid < 64) {
        const float tot = L[0][tid] + L[1][tid] + L[2][tid] + L[3][tid];
        L[0][tid] = tot;
    }
    __syncthreads();
    if (tid < 64) {
        float r = (tid < 32) ? L[0][tid] / L[0][32 + tid] : 0.0f;
        #pragma unroll
        for (int off = 32; off; off >>= 1)
            r += __shfl_xor(r, off);
        if (tid == 0) out[0] = (float)(NN * KK) - r;
    }
}

extern "C" void kernel_launch(void* const* d_in, const int* in_sizes, int n_in,
                              void* d_out, int out_size, void* d_ws, size_t ws_size,
                              hipStream_t stream) {
    const float* pred     = (const float*)d_in[0];
    const float* imgs     = (const float*)d_in[1];
    const long long* hs   = (const long long*)d_in[2];
    const long long* wsm  = (const long long*)d_in[3];
    const int S = in_sizes[2];
    float* acc   = (float*)d_ws;                       // 16 KB stripes
    int* counter = (int*)((char*)d_ws + NSTRIPE * 64 * sizeof(float));
    float* out   = (float*)d_out;

    dim3 grid((S + 1) / 2, NN);
    const int totalBlocks = grid.x * grid.y;

    hipMemsetAsync(d_ws, 0, NSTRIPE * 64 * sizeof(float) + sizeof(int), stream);
    ncut_fused<<<grid, 256, 0, stream>>>(pred, imgs, hs, wsm, acc, counter, out,
                                         S, totalBlocks);
}

// Round 8
// 37.229 us; speedup vs baseline: 2.4198x; 2.4198x over previous
//
#include <hip/hip_runtime.h>

// NcutLoss: N=4, K=8, C=3, H=W=1024, S=1000, R=5, P=81 disk points.
// loss = N*K - sum_{n,k} num[n,k]/den[n,k]
//   num[n,k] = sum_{s,p} wgt*q*pc ; den[n,k] = sum_s pc*sum_p wgt
//   wgt = exp(-d2/SIGMA_I^2 - (di^2+dj^2)/SIGMA_X^2)
//
// R7: fence-free 2-node graph. R5 gather core (2 waves per (n,s) split by
// disk row, 8000 waves). NO atomics, NO memset: each (bx,sl,n) writes its 16
// partials to an exclusive d_ws slot with plain stores (half=1 wave hands its
// 9 sums to half=0 via LDS). Final kernel reduces 4000x16 floats with fully
// coalesced 256B/wave reads. R6 lesson: device-scope fences evicted L2/L3
// residency (36MB HBM refetch/dispatch at 305GB/s) -> never fence hot path.

constexpr int P = 81;
constexpr int WW = 1024;
constexpr size_t HW = (size_t)1024 * 1024;
constexpr int NN = 4, KK = 8, CC = 3;
constexpr float INV_SI2 = 1.0f / 100.0f;  // 1/SIGMA_I^2
constexpr float INV_SX2 = 1.0f / 16.0f;   // 1/SIGMA_X^2

// Disk offsets, row-major over di=-5..5. p 0..34: rows -5..-1 (35 pts),
// p 35..80: rows 0..+5 (46 pts).
__device__ __constant__ signed char c_di[P] = {
    -5,
    -4,-4,-4,-4,-4,-4,-4,
    -3,-3,-3,-3,-3,-3,-3,-3,-3,
    -2,-2,-2,-2,-2,-2,-2,-2,-2,
    -1,-1,-1,-1,-1,-1,-1,-1,-1,
     0, 0, 0, 0, 0, 0, 0, 0, 0, 0, 0,
     1, 1, 1, 1, 1, 1, 1, 1, 1,
     2, 2, 2, 2, 2, 2, 2, 2, 2,
     3, 3, 3, 3, 3, 3, 3, 3, 3,
     4, 4, 4, 4, 4, 4, 4,
     5
};
__device__ __constant__ signed char c_dj[P] = {
     0,
    -3,-2,-1, 0, 1, 2, 3,
    -4,-3,-2,-1, 0, 1, 2, 3, 4,
    -4,-3,-2,-1, 0, 1, 2, 3, 4,
    -4,-3,-2,-1, 0, 1, 2, 3, 4,
    -5,-4,-3,-2,-1, 0, 1, 2, 3, 4, 5,
    -4,-3,-2,-1, 0, 1, 2, 3, 4,
    -4,-3,-2,-1, 0, 1, 2, 3, 4,
    -4,-3,-2,-1, 0, 1, 2, 3, 4,
    -3,-2,-1, 0, 1, 2, 3,
     0
};

__global__ __launch_bounds__(256) void ncut_accum(
    const float* __restrict__ pred,   // (N,K,H,W)
    const float* __restrict__ imgs,   // (N,C,H,W)
    const long long* __restrict__ hs, // (S,)
    const long long* __restrict__ wsm,// (S,)
    float* __restrict__ slots,        // (gridX*2*NN) entries x 16 floats
    int S)
{
    __shared__ float xfer[2][9];      // half=1 wave's {qw[0..7], wsum} per sl
    const int tid  = threadIdx.x;
    const int lane = tid & 63;
    const int wv   = tid >> 6;        // 0..3
    const int sl   = wv >> 1;         // local sample 0..1
    const int half = wv & 1;          // 0: disk rows -5..-1 (+epilogue), 1: rows 0..+5

    const int n = blockIdx.y;
    const int s = blockIdx.x * 2 + sl;
    const bool act = (s < S);

    float wsum = 0.0f;
    float qw[KK] = {0.f,0.f,0.f,0.f,0.f,0.f,0.f,0.f};
    float pv = 0.0f;

    if (act) {
        const int h = (int)hs[s] + 5;
        const int w = (int)wsm[s] + 5;
        const float* img_n = imgs + (size_t)n * CC * HW;
        const size_t coff = (size_t)h * WW + w;
        const float* pn = pred + (size_t)n * KK * HW;

        // Center preds: only the epilogue wave needs them (lanes 0..7),
        // issued first so latency hides under the gather.
        if (half == 0 && lane < KK) pv = pn[(size_t)lane * HW + coff];

        const float c0 = img_n[coff];
        const float c1 = img_n[HW + coff];
        const float c2 = img_n[2 * HW + coff];

        const int base = half ? 35 : 0;
        const int npts = half ? 46 : 35;

        if (lane < npts) {
            const int p  = base + lane;
            const int di = (int)c_di[p];
            const int dj = (int)c_dj[p];
            const size_t off = (size_t)(h + di) * WW + (w + dj);
            const float d0 = img_n[off]          - c0;
            const float d1 = img_n[HW + off]     - c1;
            const float d2 = img_n[2 * HW + off] - c2;
            const float r2 = (float)(di * di + dj * dj);
            const float wgt = __expf(-((d0*d0 + d1*d1 + d2*d2) * INV_SI2
                                       + r2 * INV_SX2));
            wsum = wgt;
            const float* qb = pn + off;
            #pragma unroll
            for (int k = 0; k < KK; ++k)
                qw[k] = wgt * qb[(size_t)k * HW];
        }

        // 64-lane butterfly over 9 values; all lanes end with wave totals.
        #pragma unroll
        for (int off = 32; off; off >>= 1) {
            wsum += __shfl_xor(wsum, off);
            #pragma unroll
            for (int k = 0; k < KK; ++k)
                qw[k] += __shfl_xor(qw[k], off);
        }
    }

    // half=1 publishes its 9 totals (zeros if inactive). Static-index select:
    // lane j<8 -> qw[j], lane 8 -> wsum (avoid dynamic reg indexing).
    float pubv = wsum;
    #pragma unroll
    for (int j = 0; j < KK; ++j)
        if (lane == j) pubv = qw[j];
    if (half == 1 && lane < 9) xfer[sl][lane] = pubv;
    __syncthreads();

    // half=0 epilogue: 16 lanes write 16 consecutive floats (plain stores,
    // exclusive slot per (bx, sl, n) -> no init, no atomics).
    if (half == 0 && lane < 16) {
        const int k = lane & 7;
        const float pvv = __shfl(pv, k);      // pv[k] from lane k
        float q = qw[0];
        #pragma unroll
        for (int j = 1; j < KK; ++j)
            if (k == j) q = qw[j];
        const float qtot = q    + xfer[sl][k];
        const float wtot = wsum + xfer[sl][8];
        const float val  = (lane < 8) ? pvv * qtot : pvv * wtot;
        // entry = (bx*2+sl)*NN + n  -> n varies fastest across entries
        const size_t e = (size_t)(blockIdx.x * 2 + sl) * NN + n;
        slots[e * 16 + lane] = val;
    }
}

__global__ __launch_bounds__(256) void ncut_final(
    const float* __restrict__ slots, float* __restrict__ out, int nent)
{
    // Entry e has n = e & 3 (n fastest). Thread (g=tid>>4, c=tid&15) reduces
    // entries e = g, g+16, ... -> all share n = g&3. Wave reads 256B/iter.
    __shared__ float sh[16][16];
    __shared__ float M[64];
    const int tid = threadIdx.x;   // 256
    const int g = tid >> 4, c = tid & 15;
    float v = 0.0f;
    #pragma unroll 4
    for (int e = g; e < nent; e += 16)
        v += slots[(size_t)e * 16 + c];
    sh[g][c] = v;
    __syncthreads();
    if (tid < 64) {
        const int n = tid >> 4, cc = tid & 15;
        M[tid] = sh[n][cc] + sh[n + 4][cc] + sh[n + 8][cc] + sh[n + 12][cc];
    }
    __syncthreads();
    if (tid < 32) {
        const int n = tid >> 3, k = tid & 7;
        float r = M[n * 16 + k] / M[n * 16 + 8 + k];
        #pragma unroll
        for (int off = 16; off; off >>= 1)
            r += __shfl_xor(r, off);
        if (tid == 0) out[0] = (float)(NN * KK) - r;
    }
}

extern "C" void kernel_launch(void* const* d_in, const int* in_sizes, int n_in,
                              void* d_out, int out_size, void* d_ws, size_t ws_size,
                              hipStream_t stream) {
    const float* pred     = (const float*)d_in[0];
    const float* imgs     = (const float*)d_in[1];
    const long long* hs   = (const long long*)d_in[2];
    const long long* wsm  = (const long long*)d_in[3];
    const int S = in_sizes[2];
    float* slots = (float*)d_ws;   // gridX*2*NN entries x 16 floats (256 KB @ S=1000)
    float* out   = (float*)d_out;

    dim3 grid((S + 1) / 2, NN);    // 4 waves/block: 2 samples x 2 disk-row halves
    const int nent = grid.x * 2 * NN;
    ncut_accum<<<grid, 256, 0, stream>>>(pred, imgs, hs, wsm, slots, S);
    ncut_final<<<1, 256, 0, stream>>>(slots, out, nent);
}

// Round 9
// 21.635 us; speedup vs baseline: 4.1639x; 1.7208x over previous
//
#include <hip/hip_runtime.h>

// NcutLoss: N=4, K=8, C=3, H=W=1024, S=1000, R=5, P=81 disk points.
// loss = N*K - sum_{n,k} num[n,k]/den[n,k]
//   num[n,k] = sum_{s,p} wgt*q*pc ; den[n,k] = sum_s pc*sum_p wgt
//   wgt = exp(-d2/SIGMA_I^2 - (di^2+dj^2)/SIGMA_X^2)
//
// R8: 2-node fence-free graph, small slots + parallel final.
//  - accum: 512-thr blocks = 4 samples x 2 disk-row halves (R5 gather core).
//    In-block LDS reduce -> one 64B slot per (block,n). No atomics/memset.
//  - final: 1024 thr, coalesced 16-iter read of 1000x16 floats, 2-stage LDS.
// R6 lesson kept: no device-scope fences (they evict L2/L3 residency).
// R7 lesson kept: 1-block strided final over big arrays costs ~10us.

constexpr int P = 81;
constexpr int WW = 1024;
constexpr size_t HW = (size_t)1024 * 1024;
constexpr int NN = 4, KK = 8, CC = 3;
constexpr float INV_SI2 = 1.0f / 100.0f;  // 1/SIGMA_I^2
constexpr float INV_SX2 = 1.0f / 16.0f;   // 1/SIGMA_X^2

// Disk offsets, row-major over di=-5..5. p 0..34: rows -5..-1 (35 pts),
// p 35..80: rows 0..+5 (46 pts).
__device__ __constant__ signed char c_di[P] = {
    -5,
    -4,-4,-4,-4,-4,-4,-4,
    -3,-3,-3,-3,-3,-3,-3,-3,-3,
    -2,-2,-2,-2,-2,-2,-2,-2,-2,
    -1,-1,-1,-1,-1,-1,-1,-1,-1,
     0, 0, 0, 0, 0, 0, 0, 0, 0, 0, 0,
     1, 1, 1, 1, 1, 1, 1, 1, 1,
     2, 2, 2, 2, 2, 2, 2, 2, 2,
     3, 3, 3, 3, 3, 3, 3, 3, 3,
     4, 4, 4, 4, 4, 4, 4,
     5
};
__device__ __constant__ signed char c_dj[P] = {
     0,
    -3,-2,-1, 0, 1, 2, 3,
    -4,-3,-2,-1, 0, 1, 2, 3, 4,
    -4,-3,-2,-1, 0, 1, 2, 3, 4,
    -4,-3,-2,-1, 0, 1, 2, 3, 4,
    -5,-4,-3,-2,-1, 0, 1, 2, 3, 4, 5,
    -4,-3,-2,-1, 0, 1, 2, 3, 4,
    -4,-3,-2,-1, 0, 1, 2, 3, 4,
    -4,-3,-2,-1, 0, 1, 2, 3, 4,
    -3,-2,-1, 0, 1, 2, 3,
     0
};

__global__ __launch_bounds__(512) void ncut_accum(
    const float* __restrict__ pred,   // (N,K,H,W)
    const float* __restrict__ imgs,   // (N,C,H,W)
    const long long* __restrict__ hs, // (S,)
    const long long* __restrict__ wsm,// (S,)
    float* __restrict__ slots,        // (gridX*NN) entries x 16 floats
    int S)
{
    __shared__ float xfer[4][9];      // half=1 totals {qw[0..7], wsum} per sl
    __shared__ float arr[4][16];      // half=0 epilogue values per sl
    const int tid  = threadIdx.x;
    const int lane = tid & 63;
    const int wv   = tid >> 6;        // 0..7
    const int sl   = wv >> 1;         // local sample 0..3
    const int half = wv & 1;          // 0: disk rows -5..-1 (+epilogue), 1: rows 0..+5

    const int n = blockIdx.y;
    const int s = blockIdx.x * 4 + sl;
    const bool act = (s < S);

    float wsum = 0.0f;
    float qw[KK] = {0.f,0.f,0.f,0.f,0.f,0.f,0.f,0.f};
    float pv = 0.0f;

    if (act) {
        const int h = (int)hs[s] + 5;
        const int w = (int)wsm[s] + 5;
        const float* img_n = imgs + (size_t)n * CC * HW;
        const size_t coff = (size_t)h * WW + w;
        const float* pn = pred + (size_t)n * KK * HW;

        // Center preds: epilogue wave only, issued first (hidden under gather).
        if (half == 0 && lane < KK) pv = pn[(size_t)lane * HW + coff];

        const float c0 = img_n[coff];
        const float c1 = img_n[HW + coff];
        const float c2 = img_n[2 * HW + coff];

        const int base = half ? 35 : 0;
        const int npts = half ? 46 : 35;

        if (lane < npts) {
            const int p  = base + lane;
            const int di = (int)c_di[p];
            const int dj = (int)c_dj[p];
            const size_t off = (size_t)(h + di) * WW + (w + dj);
            const float d0 = img_n[off]          - c0;
            const float d1 = img_n[HW + off]     - c1;
            const float d2 = img_n[2 * HW + off] - c2;
            const float r2 = (float)(di * di + dj * dj);
            const float wgt = __expf(-((d0*d0 + d1*d1 + d2*d2) * INV_SI2
                                       + r2 * INV_SX2));
            wsum = wgt;
            const float* qb = pn + off;
            #pragma unroll
            for (int k = 0; k < KK; ++k)
                qw[k] = wgt * qb[(size_t)k * HW];
        }

        // 64-lane butterfly over 9 values; all lanes end with wave totals.
        #pragma unroll
        for (int off = 32; off; off >>= 1) {
            wsum += __shfl_xor(wsum, off);
            #pragma unroll
            for (int k = 0; k < KK; ++k)
                qw[k] += __shfl_xor(qw[k], off);
        }
    }

    // half=1 publishes its 9 totals (zeros if inactive). Static-index select.
    float pubv = wsum;
    #pragma unroll
    for (int j = 0; j < KK; ++j)
        if (lane == j) pubv = qw[j];
    if (half == 1 && lane < 9) xfer[sl][lane] = pubv;
    __syncthreads();

    // half=0 epilogue: 16 lanes produce the sample's 16 values.
    if (half == 0 && lane < 16) {
        const int k = lane & 7;
        const float pvv = __shfl(pv, k);      // pv[k] from lane k
        float q = qw[0];
        #pragma unroll
        for (int j = 1; j < KK; ++j)
            if (k == j) q = qw[j];
        const float qtot = q    + xfer[sl][k];
        const float wtot = wsum + xfer[sl][8];
        arr[sl][lane] = (lane < 8) ? pvv * qtot : pvv * wtot;
    }
    __syncthreads();

    // One 64B slot per (block, n): entry = bx*NN + n (n fastest).
    if (tid < 16) {
        const float sum = arr[0][tid] + arr[1][tid] + arr[2][tid] + arr[3][tid];
        slots[((size_t)blockIdx.x * NN + n) * 16 + tid] = sum;
    }
}

__global__ __launch_bounds__(1024) void ncut_final(
    const float* __restrict__ slots, float* __restrict__ out, int nent)
{
    // Entry e: n = e & 3. Thread (g=tid>>4, c=tid&15) reduces e = g + 64t;
    // e&3 == g&3 is invariant. Each iteration: 1024 consecutive floats.
    __shared__ float sh[64][16];
    __shared__ float M[64];
    const int tid = threadIdx.x;   // 1024
    const int g = tid >> 4, c = tid & 15;
    float v = 0.0f;
    #pragma unroll 4
    for (int e = g; e < nent; e += 64)
        v += slots[(size_t)e * 16 + c];
    sh[g][c] = v;
    __syncthreads();
    if (tid < 64) {
        const int n = tid >> 4, cc = tid & 15;
        float t = 0.0f;
        #pragma unroll
        for (int j = 0; j < 16; ++j)
            t += sh[n + 4 * j][cc];
        M[tid] = t;
    }
    __syncthreads();
    if (tid < 32) {
        const int n = tid >> 3, k = tid & 7;
        float r = M[n * 16 + k] / M[n * 16 + 8 + k];
        #pragma unroll
        for (int off = 16; off; off >>= 1)
            r += __shfl_xor(r, off);
        if (tid == 0) out[0] = (float)(NN * KK) - r;
    }
}

extern "C" void kernel_launch(void* const* d_in, const int* in_sizes, int n_in,
                              void* d_out, int out_size, void* d_ws, size_t ws_size,
                              hipStream_t stream) {
    const float* pred     = (const float*)d_in[0];
    const float* imgs     = (const float*)d_in[1];
    const long long* hs   = (const long long*)d_in[2];
    const long long* wsm  = (const long long*)d_in[3];
    const int S = in_sizes[2];
    float* slots = (float*)d_ws;   // gridX*NN entries x 16 floats (64 KB @ S=1000)
    float* out   = (float*)d_out;

    dim3 grid((S + 3) / 4, NN);    // 8 waves/block: 4 samples x 2 disk-row halves
    const int nent = grid.x * NN;
    ncut_accum<<<grid, 512, 0, stream>>>(pred, imgs, hs, wsm, slots, S);
    ncut_final<<<1, 1024, 0, stream>>>(slots, out, nent);
}

// Round 10
// 20.866 us; speedup vs baseline: 4.3175x; 1.0369x over previous
//
#include <hip/hip_runtime.h>

// NcutLoss: N=4, K=8, C=3, H=W=1024, S=1000, R=5, P=81 disk points.
// loss = N*K - sum_{n,k} num[n,k]/den[n,k]
//   num[n,k] = sum_{s,p} wgt*q*pc ; den[n,k] = sum_s pc*sum_p wgt
//   wgt = exp(-d2/SIGMA_I^2 - (di^2+dj^2)/SIGMA_X^2)
//
// R9: harvest the reduction tail. 1024-thr accum blocks = 8 samples x 2
// disk-row halves (16 waves); slots shrink to 500 x 64B; final reads 8
// coalesced iterations. Gather core identical to R5/R8 (best measured).
// Kept lessons: no device-scope fences (R6: evicts L2/L3 residency, 36MB HBM
// refetch); no 1-block strided final (R7: +10us); fence-free exclusive-slot
// stores, no atomics, no memset.

constexpr int P = 81;
constexpr int WW = 1024;
constexpr size_t HW = (size_t)1024 * 1024;
constexpr int NN = 4, KK = 8, CC = 3;
constexpr float INV_SI2 = 1.0f / 100.0f;  // 1/SIGMA_I^2
constexpr float INV_SX2 = 1.0f / 16.0f;   // 1/SIGMA_X^2

// Disk offsets, row-major over di=-5..5. p 0..34: rows -5..-1 (35 pts),
// p 35..80: rows 0..+5 (46 pts).
__device__ __constant__ signed char c_di[P] = {
    -5,
    -4,-4,-4,-4,-4,-4,-4,
    -3,-3,-3,-3,-3,-3,-3,-3,-3,
    -2,-2,-2,-2,-2,-2,-2,-2,-2,
    -1,-1,-1,-1,-1,-1,-1,-1,-1,
     0, 0, 0, 0, 0, 0, 0, 0, 0, 0, 0,
     1, 1, 1, 1, 1, 1, 1, 1, 1,
     2, 2, 2, 2, 2, 2, 2, 2, 2,
     3, 3, 3, 3, 3, 3, 3, 3, 3,
     4, 4, 4, 4, 4, 4, 4,
     5
};
__device__ __constant__ signed char c_dj[P] = {
     0,
    -3,-2,-1, 0, 1, 2, 3,
    -4,-3,-2,-1, 0, 1, 2, 3, 4,
    -4,-3,-2,-1, 0, 1, 2, 3, 4,
    -4,-3,-2,-1, 0, 1, 2, 3, 4,
    -5,-4,-3,-2,-1, 0, 1, 2, 3, 4, 5,
    -4,-3,-2,-1, 0, 1, 2, 3, 4,
    -4,-3,-2,-1, 0, 1, 2, 3, 4,
    -4,-3,-2,-1, 0, 1, 2, 3, 4,
    -3,-2,-1, 0, 1, 2, 3,
     0
};

__global__ __launch_bounds__(1024) void ncut_accum(
    const float* __restrict__ pred,   // (N,K,H,W)
    const float* __restrict__ imgs,   // (N,C,H,W)
    const long long* __restrict__ hs, // (S,)
    const long long* __restrict__ wsm,// (S,)
    float* __restrict__ slots,        // (gridX*NN) entries x 16 floats
    int S)
{
    __shared__ float xfer[8][9];      // half=1 totals {qw[0..7], wsum} per sl
    __shared__ float arr[8][16];      // half=0 epilogue values per sl
    const int tid  = threadIdx.x;
    const int lane = tid & 63;
    const int wv   = tid >> 6;        // 0..15
    const int sl   = wv >> 1;         // local sample 0..7
    const int half = wv & 1;          // 0: disk rows -5..-1 (+epilogue), 1: rows 0..+5

    const int n = blockIdx.y;
    const int s = blockIdx.x * 8 + sl;
    const bool act = (s < S);

    float wsum = 0.0f;
    float qw[KK] = {0.f,0.f,0.f,0.f,0.f,0.f,0.f,0.f};
    float pv = 0.0f;

    if (act) {
        const int h = (int)hs[s] + 5;
        const int w = (int)wsm[s] + 5;
        const float* img_n = imgs + (size_t)n * CC * HW;
        const size_t coff = (size_t)h * WW + w;
        const float* pn = pred + (size_t)n * KK * HW;

        // Center preds: epilogue wave only, issued first (hidden under gather).
        if (half == 0 && lane < KK) pv = pn[(size_t)lane * HW + coff];

        const float c0 = img_n[coff];
        const float c1 = img_n[HW + coff];
        const float c2 = img_n[2 * HW + coff];

        const int base = half ? 35 : 0;
        const int npts = half ? 46 : 35;

        if (lane < npts) {
            const int p  = base + lane;
            const int di = (int)c_di[p];
            const int dj = (int)c_dj[p];
            const size_t off = (size_t)(h + di) * WW + (w + dj);
            const float d0 = img_n[off]          - c0;
            const float d1 = img_n[HW + off]     - c1;
            const float d2 = img_n[2 * HW + off] - c2;
            const float r2 = (float)(di * di + dj * dj);
            const float wgt = __expf(-((d0*d0 + d1*d1 + d2*d2) * INV_SI2
                                       + r2 * INV_SX2));
            wsum = wgt;
            const float* qb = pn + off;
            #pragma unroll
            for (int k = 0; k < KK; ++k)
                qw[k] = wgt * qb[(size_t)k * HW];
        }

        // 64-lane butterfly over 9 values; all lanes end with wave totals.
        #pragma unroll
        for (int off = 32; off; off >>= 1) {
            wsum += __shfl_xor(wsum, off);
            #pragma unroll
            for (int k = 0; k < KK; ++k)
                qw[k] += __shfl_xor(qw[k], off);
        }
    }

    // half=1 publishes its 9 totals (zeros if inactive). Static-index select.
    float pubv = wsum;
    #pragma unroll
    for (int j = 0; j < KK; ++j)
        if (lane == j) pubv = qw[j];
    if (half == 1 && lane < 9) xfer[sl][lane] = pubv;
    __syncthreads();

    // half=0 epilogue: 16 lanes produce the sample's 16 values.
    if (half == 0 && lane < 16) {
        const int k = lane & 7;
        const float pvv = __shfl(pv, k);      // pv[k] from lane k
        float q = qw[0];
        #pragma unroll
        for (int j = 1; j < KK; ++j)
            if (k == j) q = qw[j];
        const float qtot = q    + xfer[sl][k];
        const float wtot = wsum + xfer[sl][8];
        arr[sl][lane] = (lane < 8) ? pvv * qtot : pvv * wtot;
    }
    __syncthreads();

    // One 64B slot per (block, n): entry = bx*NN + n (n fastest).
    if (tid < 16) {
        float sum = 0.0f;
        #pragma unroll
        for (int j = 0; j < 8; ++j)
            sum += arr[j][tid];
        slots[((size_t)blockIdx.x * NN + n) * 16 + tid] = sum;
    }
}

__global__ __launch_bounds__(1024) void ncut_final(
    const float* __restrict__ slots, float* __restrict__ out, int nent)
{
    // Entry e: n = e & 3. Thread (g=tid>>4, c=tid&15) reduces e = g + 64t;
    // e&3 == g&3 invariant. Each iteration reads 4KB fully coalesced.
    __shared__ float sh[64][16];
    __shared__ float M[64];
    const int tid = threadIdx.x;   // 1024
    const int g = tid >> 4, c = tid & 15;
    float v = 0.0f;
    #pragma unroll 4
    for (int e = g; e < nent; e += 64)
        v += slots[(size_t)e * 16 + c];
    sh[g][c] = v;
    __syncthreads();
    if (tid < 64) {
        const int n = tid >> 4, cc = tid & 15;
        float t = 0.0f;
        #pragma unroll
        for (int j = 0; j < 16; ++j)
            t += sh[n + 4 * j][cc];
        M[tid] = t;
    }
    __syncthreads();
    if (tid < 32) {
        const int n = tid >> 3, k = tid & 7;
        float r = M[n * 16 + k] / M[n * 16 + 8 + k];
        #pragma unroll
        for (int off = 16; off; off >>= 1)
            r += __shfl_xor(r, off);
        if (tid == 0) out[0] = (float)(NN * KK) - r;
    }
}

extern "C" void kernel_launch(void* const* d_in, const int* in_sizes, int n_in,
                              void* d_out, int out_size, void* d_ws, size_t ws_size,
                              hipStream_t stream) {
    const float* pred     = (const float*)d_in[0];
    const float* imgs     = (const float*)d_in[1];
    const long long* hs   = (const long long*)d_in[2];
    const long long* wsm  = (const long long*)d_in[3];
    const int S = in_sizes[2];
    float* slots = (float*)d_ws;   // gridX*NN entries x 16 floats (32 KB @ S=1000)
    float* out   = (float*)d_out;

    dim3 grid((S + 7) / 8, NN);    // 16 waves/block: 8 samples x 2 disk-row halves
    const int nent = grid.x * NN;
    ncut_accum<<<grid, 1024, 0, stream>>>(pred, imgs, hs, wsm, slots, S);
    ncut_final<<<1, 1024, 0, stream>>>(slots, out, nent);
}